// Round 12
// baseline (214.589 us; speedup 1.0000x reference)
//
#include <hip/hip_runtime.h>

typedef unsigned int u32;
typedef unsigned short u16;
typedef __attribute__((ext_vector_type(8))) short bf16x8;   // 8 bf16 in 4 VGPRs
typedef __attribute__((ext_vector_type(4))) float f32x4;

#define NPTS 4096
#define DIM  64
#define NB   32          // 4096/128
#define TS   128
#define NBLK 528         // NB*(NB+1)/2 upper-tri blocks (final_k only)
#define WLO16 0x4140u    // window low: float bits 0x41400000 = 12.0
#define NWBIN 832        // t16 in [0x4140, 0x4480) -> D in [12, 1024)
#define RSTR 836         // replica stride in u32 (834 bins + 2 pad, 16B aligned)
#define NREP 512         // per-z histogram replicas (one per hist block)

// map linear upper-tri block id -> (by,bx), bx>=by  (final_k)
__device__ __forceinline__ void bmap(int b, int& by, int& bx){
  by = 0;
  while (b >= NB - by){ b -= NB - by; by++; }
  bx = by + b;
}

// fp32 -> bf16 bits, round-nearest-even
__device__ __forceinline__ u16 f2bf(float x){
  u32 u = __float_as_uint(x);
  return (u16)((u + 0x7fffu + ((u>>16)&1u)) >> 16);
}

// ---------- pre-pass: X,Y -> bf16 rows + fp32 squared norms ----------
__global__ __launch_bounds__(256) void convert_k(const float* __restrict__ X, const float* __restrict__ Y,
                                                 u16* __restrict__ Xbf, float* __restrict__ Gall){
  int t = blockIdx.x*256 + threadIdx.x;     // 8192 threads, one row each
  int z = t >> 12, row = t & 4095;
  const float* src = (z ? Y : X) + (size_t)row*DIM;
  u16* dst = Xbf + (size_t)t*DIM;
  float g = 0.f;
#pragma unroll
  for (int k=0;k<DIM;k+=4){
    float4 f = *(const float4*)(src+k);
    g = fmaf(f.x,f.x,g); g = fmaf(f.y,f.y,g); g = fmaf(f.z,f.z,g); g = fmaf(f.w,f.w,g);
    ushort4 h; h.x=f2bf(f.x); h.y=f2bf(f.y); h.z=f2bf(f.z); h.w=f2bf(f.w);
    *(ushort4*)(dst+k) = h;
  }
  Gall[t] = g;
}

// ---------- pass 1: full-matrix panel histogram, plain-stored per-block (NO global atomics) ----------
// block = (z, panel pa of 16 rows, column-half ch of 2048 cols); wave covers 16x128 per iter.
// A-op/B-op lane layout and MFMA order identical to validated dtile1 (rounds 7-11, absmax 0.0).
__global__ __launch_bounds__(256,2) void hist_k(const u16* __restrict__ Xbf, const float* __restrict__ Gall,
                                                u32* __restrict__ histbuf){
  __shared__ u32 lh[RSTR];
  int z = blockIdx.y, tid = threadIdx.x;
  int pb = blockIdx.x;              // 0..511
  int pa = pb >> 1, ch = pb & 1;
  int w=tid>>6, lane=tid&63, q=lane>>4, nl=lane&15;
  for (int t=tid;t<RSTR;t+=256) lh[t]=0;
  __syncthreads();
  const bf16x8* Xb = (const bf16x8*)Xbf + (size_t)z*NPTS*8;
  const float* Gz = Gall + z*NPTS;
  int rowA = pa*16 + nl;
  bf16x8 af0 = Xb[(size_t)rowA*8 + q];
  bf16x8 af1 = Xb[(size_t)rowA*8 + 4 + q];
  float ga = Gz[rowA];
  float gAm[4];
#pragma unroll
  for (int r=0;r<4;r++) gAm[r] = __shfl(ga, q*4+r, 64);
  for (int it=0; it<4; ++it){
    int j0 = ch*2048 + (it*4 + w)*128;
    f32x4 acc[8];
#pragma unroll
    for (int b=0;b<8;b++) acc[b] = (f32x4)0.0f;
#pragma unroll
    for (int tb=0;tb<8;tb++){
      int jrow = j0 + tb*16 + nl;
      acc[tb] = __builtin_amdgcn_mfma_f32_16x16x32_bf16(af0, Xb[(size_t)jrow*8 + q],     acc[tb], 0,0,0);
      acc[tb] = __builtin_amdgcn_mfma_f32_16x16x32_bf16(af1, Xb[(size_t)jrow*8 + 4 + q], acc[tb], 0,0,0);
    }
#pragma unroll
    for (int tb=0;tb<8;tb++){
      int j = j0 + tb*16 + nl;
      float gb = Gz[j];
#pragma unroll
      for (int r=0;r<4;r++){
        int i = pa*16 + q*4 + r;
        float d = (gAm[r] + gb) - 2.0f*acc[tb][r];
        if (i==j) d = 0.f;                       // diag -> bin 0 (below window)
        u32 t16 = __float_as_uint(d) >> 16;
        u32 bin = (t16 < WLO16) ? 0u
                : (t16 >= WLO16+NWBIN) ? (u32)(NWBIN+1)
                : (t16 - WLO16 + 1u);
        atomicAdd(&lh[bin], 1u);
      }
    }
  }
  __syncthreads();
  u32* dst = histbuf + ((size_t)z*NREP + pb)*RSTR;
  for (int t=tid;t<RSTR;t+=256) dst[t] = lh[t];
}

// ---------- sum replicas + parallel select + interpolate ----------
// full-matrix ranks: kf = 4096 (diag zeros) + 2*k_uppertri (every pair counted twice)
__global__ __launch_bounds__(256) void scan16i(const u32* __restrict__ histbuf,
                                               float* __restrict__ scal,
                                               u32 kf1, u32 kf2){
  int z = blockIdx.x;
  int tid = threadIdx.x;
  __shared__ u32 wsum[4];
  __shared__ double svals[2];
  u32 c4[4] = {0,0,0,0};
  if (tid < 209){
    const u32* base = histbuf + (size_t)z*NREP*RSTR + 4*tid;
    for (int rep=0; rep<NREP; rep+=4){
      uint4 v0 = *(const uint4*)(base + (size_t)(rep+0)*RSTR);
      uint4 v1 = *(const uint4*)(base + (size_t)(rep+1)*RSTR);
      uint4 v2 = *(const uint4*)(base + (size_t)(rep+2)*RSTR);
      uint4 v3 = *(const uint4*)(base + (size_t)(rep+3)*RSTR);
      c4[0] += v0.x+v1.x+v2.x+v3.x;
      c4[1] += v0.y+v1.y+v2.y+v3.y;
      c4[2] += v0.z+v1.z+v2.z+v3.z;
      c4[3] += v0.w+v1.w+v2.w+v3.w;
    }
  }
  u32 s = c4[0]+c4[1]+c4[2]+c4[3];
  int lane = tid & 63, wv = tid >> 6;
  u32 pre = s;
#pragma unroll
  for (int off=1; off<64; off<<=1){
    u32 t2 = __shfl_up(pre, off, 64);
    if (lane >= off) pre += t2;
  }
  if (lane==63) wsum[wv] = pre;
  __syncthreads();
  u32 base2 = 0;
  for (int k=0;k<wv;k++) base2 += wsum[k];
  u32 incl = base2 + pre, excl = incl - s;
  u32 ks[2] = {kf1,kf2};
#pragma unroll
  for (int w2=0; w2<2; w2++){
    if (ks[w2] >= excl && ks[w2] < incl){
      u32 acc = excl;
#pragma unroll
      for (int j=0;j<4;j++){
        if (ks[w2] < acc + c4[j]){
          int b = tid*4 + j;
          double lo, hi;
          if (b==0){ lo=12.0; hi=12.0; }
          else if (b>=NWBIN+1){ lo=1024.0; hi=1024.0; }
          else {
            u32 t16 = WLO16 + (u32)b - 1u;
            lo = (double)__uint_as_float(t16<<16);
            hi = (double)__uint_as_float((t16+1u)<<16);
          }
          double frac = ((double)(ks[w2]-acc) + 0.5)/(double)c4[j];
          svals[w2] = lo + (hi-lo)*frac;
          break;
        }
        acc += c4[j];
      }
    }
  }
  __syncthreads();
  if (tid==0){
    float med = (float)(0.5*(svals[0]+svals[1]));
    float wd = sqrtf(0.5f*med);
    scal[z] = 2.0f*wd*wd;
  }
}

// ---------- pass 2: full-matrix panel row sums, plain stores (NO atomics) ----------
__global__ __launch_bounds__(256,2) void rowsum_k(const u16* __restrict__ Xbf, const float* __restrict__ Gall,
                                                  const float* __restrict__ scal,
                                                  double* __restrict__ rowpart){   // [z*2+ch][4096]
  int z = blockIdx.y, tid = threadIdx.x;
  int pb = blockIdx.x;
  int pa = pb >> 1, ch = pb & 1;
  int w=tid>>6, lane=tid&63, q=lane>>4, nl=lane&15;
  const bf16x8* Xb = (const bf16x8*)Xbf + (size_t)z*NPTS*8;
  const float* Gz = Gall + z*NPTS;
  float negi = -1.0f/scal[z];
  int rowA = pa*16 + nl;
  bf16x8 af0 = Xb[(size_t)rowA*8 + q];
  bf16x8 af1 = Xb[(size_t)rowA*8 + 4 + q];
  float ga = Gz[rowA];
  float gAm[4];
#pragma unroll
  for (int r=0;r<4;r++) gAm[r] = __shfl(ga, q*4+r, 64);
  double rs[4] = {0,0,0,0};
  for (int it=0; it<4; ++it){
    int j0 = ch*2048 + (it*4 + w)*128;
    f32x4 acc[8];
#pragma unroll
    for (int b=0;b<8;b++) acc[b] = (f32x4)0.0f;
#pragma unroll
    for (int tb=0;tb<8;tb++){
      int jrow = j0 + tb*16 + nl;
      acc[tb] = __builtin_amdgcn_mfma_f32_16x16x32_bf16(af0, Xb[(size_t)jrow*8 + q],     acc[tb], 0,0,0);
      acc[tb] = __builtin_amdgcn_mfma_f32_16x16x32_bf16(af1, Xb[(size_t)jrow*8 + 4 + q], acc[tb], 0,0,0);
    }
#pragma unroll
    for (int tb=0;tb<8;tb++){
      int j = j0 + tb*16 + nl;
      float gb = Gz[j];
#pragma unroll
      for (int r=0;r<4;r++){
        int i = pa*16 + q*4 + r;
        float d = (gAm[r] + gb) - 2.0f*acc[tb][r];
        if (i==j) d = 0.f;                       // exact K_ii = 1
        rs[r] += (double)expf(d*negi);
      }
    }
  }
  // reduce over nl lanes (columns within wave)
#pragma unroll
  for (int r=0;r<4;r++){
    double v2 = rs[r];
    v2 += __shfl_xor(v2,1,64); v2 += __shfl_xor(v2,2,64);
    v2 += __shfl_xor(v2,4,64); v2 += __shfl_xor(v2,8,64);
    rs[r] = v2;
  }
  __shared__ double rsum[4][16];
  if (nl==0){
#pragma unroll
    for (int r=0;r<4;r++) rsum[w][q*4+r] = rs[r];
  }
  __syncthreads();
  if (tid < 16){
    double s = rsum[0][tid]+rsum[1][tid]+rsum[2][tid]+rsum[3][tid];
    rowpart[(size_t)(z*2+ch)*NPTS + pa*16 + tid] = s;
  }
}

// ---------- combine halves -> rowK/rowL + totals ----------
__global__ __launch_bounds__(256) void reduce_rows(const double* __restrict__ rowpart,
                                                   double* __restrict__ rowK, double* __restrict__ rowL,
                                                   double* __restrict__ sums){
  __shared__ double sd[256];
  int t=threadIdx.x;
  double s0=0, s1=0;
  for (int i=t;i<NPTS;i+=256){
    double a = rowpart[i] + rowpart[NPTS+i];
    double b = rowpart[2*NPTS+i] + rowpart[3*NPTS+i];
    rowK[i]=a; rowL[i]=b;
    s0+=a; s1+=b;
  }
  sd[t]=s0; __syncthreads();
  for(int off=128;off>0;off>>=1){ if(t<off) sd[t]+=sd[t+off]; __syncthreads(); }
  if(t==0) sums[0]=sd[0];
  __syncthreads();
  sd[t]=s1; __syncthreads();
  for(int off=128;off>0;off>>=1){ if(t<off) sd[t]+=sd[t+off]; __syncthreads(); }
  if(t==0) sums[1]=sd[0];
}

// ---------- pass 3: per-column-group K,L recompute + centered products (half-tile blocks) ----------
__global__ __launch_bounds__(256,2) void final_k(const u16* __restrict__ Xbf, const float* __restrict__ Gall,
                                                 const float* __restrict__ scal,
                                                 const double* __restrict__ rowK,
                                                 const double* __restrict__ rowL,
                                                 const double* __restrict__ sums,
                                                 double* __restrict__ partials){
  int tid = threadIdx.x;
  int b = blockIdx.x >> 1, half = blockIdx.x & 1;
  int by,bx; bmap(b,by,bx);
  bool isdiag = (by==bx);
  int i0=by*TS, j0=bx*TS;
  int w=tid>>6, lane=tid&63, q=lane>>4, nl=lane&15;
  const bf16x8* Xb = (const bf16x8*)Xbf;
  const bf16x8* Yb = Xb + (size_t)NPTS*8;
  const float* Gx = Gall;
  const float* Gy = Gall + NPTS;
  const double inv_n = 1.0/(double)NPTS;
  double tmK = sums[0]*(inv_n*inv_n), tmL = sums[1]*(inv_n*inv_n);
  float negx = -1.0f/scal[0], negy = -1.0f/scal[1];
  double wgt = isdiag ? 1.0 : 2.0;
  double S1=0, S2=0, trV=0;
  int rt = half*4 + w;
  int rowA = i0 + rt*16 + nl;
  bf16x8 axf0 = Xb[(size_t)rowA*8 + q];
  bf16x8 axf1 = Xb[(size_t)rowA*8 + 4 + q];
  bf16x8 ayf0 = Yb[(size_t)rowA*8 + q];
  bf16x8 ayf1 = Yb[(size_t)rowA*8 + 4 + q];
  float gaX = Gx[rowA], gaY = Gy[rowA];
  float gXm[4], gYm[4];
#pragma unroll
  for (int r=0;r<4;r++){ gXm[r] = __shfl(gaX, q*4+r, 64); gYm[r] = __shfl(gaY, q*4+r, 64); }
  double rmKi[4], rmLi[4];
#pragma unroll
  for (int r=0;r<4;r++){
    int i = i0 + rt*16 + q*4 + r;
    rmKi[r] = rowK[i]*inv_n; rmLi[r] = rowL[i]*inv_n;
  }
#pragma unroll
  for (int tb=0;tb<8;tb++){
    int jrow = j0 + tb*16 + nl;
    f32x4 accX = (f32x4)0.0f, accY = (f32x4)0.0f;
    accX = __builtin_amdgcn_mfma_f32_16x16x32_bf16(axf0, Xb[(size_t)jrow*8 + q],     accX, 0,0,0);
    accX = __builtin_amdgcn_mfma_f32_16x16x32_bf16(axf1, Xb[(size_t)jrow*8 + 4 + q], accX, 0,0,0);
    accY = __builtin_amdgcn_mfma_f32_16x16x32_bf16(ayf0, Yb[(size_t)jrow*8 + q],     accY, 0,0,0);
    accY = __builtin_amdgcn_mfma_f32_16x16x32_bf16(ayf1, Yb[(size_t)jrow*8 + 4 + q], accY, 0,0,0);
    float gbX = Gx[jrow], gbY = Gy[jrow];
    double cmK = rowK[jrow]*inv_n - tmK;
    double cmL = rowL[jrow]*inv_n - tmL;
    int jl = tb*16 + nl;
#pragma unroll
    for (int r=0;r<4;r++){
      int il = rt*16 + q*4 + r;
      float dx = (gXm[r] + gbX) - 2.0f*accX[r];
      float dy = (gYm[r] + gbY) - 2.0f*accY[r];
      bool dg = isdiag && il==jl;
      if (dg){ dx = 0.f; dy = 0.f; }
      float kx = expf(dx*negx);
      float lv = expf(dy*negy);
      double kc = ((double)kx - rmKi[r]) - cmK;
      double lc = ((double)lv - rmLi[r]) - cmL;
      double prod = kc*lc;
      S1 += wgt*prod;
      double vv = (prod*prod)*(1.0/36.0);
      S2 += wgt*vv;
      if (dg) trV += vv;
    }
  }
  __shared__ double red[4][3];
  double vals[3]={S1,S2,trV};
  int wv = tid >> 6;
#pragma unroll
  for (int v=0;v<3;v++){
    double x = vals[v];
#pragma unroll
    for (int s2=1;s2<64;s2<<=1) x += __shfl_xor(x, s2, 64);
    if (lane==0) red[wv][v]=x;
  }
  __syncthreads();
  if (tid < 3)
    partials[(size_t)blockIdx.x*4 + tid] = red[0][tid]+red[1][tid]+red[2][tid]+red[3][tid];
}

// ---------- wave-parallel regularized lower incomplete gamma P(a,x) ----------
__device__ double gammainc_wave(double a, double x, double lga, int lane){
  double C = 1.0/a;
  double psum = 0.0;
  for (int b=0;b<8192;b++){
    double k = (double)(b*64 + lane + 1);
    double rr = x/(a+k);
    double pp = rr;
#pragma unroll
    for (int s=1;s<64;s<<=1){
      double t = __shfl_up(pp, s, 64);
      if (lane >= s) pp *= t;
    }
    double c = C*pp;
    psum += c;
    double clast = __shfl(c, 63, 64);
    double rlast = __shfl(rr, 63, 64);
    C = clast;
    if (rlast < 1.0 && clast*rlast/(1.0-rlast) < 1e-17) break;
  }
#pragma unroll
  for (int s=1;s<64;s<<=1) psum += __shfl_xor(psum, s, 64);
  double total = 1.0/a + psum;
  return exp(-x + a*log(x) - lga) * total;
}

// ---------- reduce partials + Newton ----------
__global__ __launch_bounds__(256) void finalize_k(const double* __restrict__ partials,
                                                  const double* __restrict__ sums,
                                                  float* __restrict__ out)
{
  __shared__ double red[3][4];
  __shared__ double tot[4];
  int tid = threadIdx.x;
  double v0=0,v1=0,v2=0;
  for (int i=tid; i<2*NBLK; i+=256){
    const double* p = partials + (size_t)i*4;
    v0+=p[0]; v1+=p[1]; v2+=p[2];
  }
  double vals[3]={v0,v1,v2};
  int lane = tid & 63, wv = tid >> 6;
#pragma unroll
  for (int v=0;v<3;v++){
    double x = vals[v];
#pragma unroll
    for (int s2=1;s2<64;s2<<=1) x += __shfl_xor(x, s2, 64);
    if (lane==0) red[v][wv]=x;
  }
  __syncthreads();
  if (tid==0){
#pragma unroll
    for (int v=0;v<3;v++) tot[v] = red[v][0]+red[v][1]+red[v][2]+red[v][3];
  }
  __syncthreads();
  if (tid >= 64) return;

  const double n = (double)NPTS;
  double totK=sums[0], totL=sums[1];
  double S1=tot[0], S2=tot[1], trV=tot[2];
  double testStat = S1/n;
  double varHSIC = (S2 - trV)/n/(n-1.0);
  varHSIC = varHSIC*72.0*(n-4.0)*(n-5.0)/n/(n-1.0)/(n-2.0)/(n-3.0);
  double muX = (totK-n)/n/(n-1.0);   // trace(K) = n exactly (diag forced to 1)
  double muY = (totL-n)/n/(n-1.0);
  double mHSIC = (1.0 + muX*muY - muX - muY)/n;
  double al = mHSIC*mHSIC/varHSIC;
  double bet = varHSIC*n/mHSIC;
  double p = (double)((float)(1.0-0.8));
  double lga = lgamma(al);
  double lo = 0.0, hi = al + 10.0*sqrt(al) + 100.0;
  const double zp = -0.8416212335729142957;  // Phi^-1(0.2)
  double t = 1.0 - 1.0/(9.0*al) + zp/(3.0*sqrt(al));
  double x = al*t*t*t;
  if (!(x > 0.0) || !(x < hi)) x = 0.5*hi;
  for (int it=0; it<2; ++it){
    double P = gammainc_wave(al, x, lga, lane);
    double diff = P - p;
    if (diff < 0.0) lo = x; else hi = x;
    if (fabs(diff) < 1e-12) break;
    double pdf = exp(-x + (al-1.0)*log(x) - lga);
    double nx = x - diff/pdf;
    if (!(nx > lo) || !(nx < hi)) nx = 0.5*(lo+hi);
    x = nx;
  }
  if (lane==0){
    out[0]=(float)testStat;
    out[1]=(float)(bet*x);
  }
}

// ---------- host ----------
extern "C" void kernel_launch(void* const* d_in, const int* in_sizes, int n_in,
                              void* d_out, int out_size, void* d_ws, size_t ws_size,
                              hipStream_t stream) {
  const float* X = (const float*)d_in[0];
  const float* Y = (const float*)d_in[1];
  float* out = (float*)d_out;
  char* ws = (char*)d_ws;

  double* sums     = (double*)ws;                    // 2 doubles @0
  float*  scal     = (float*)(ws + 128);             // 2 floats
  double* rowK     = (double*)(ws + 8192);           // 32 KB
  double* rowL     = (double*)(ws + 40960);          // 32 KB
  float*  Gall     = (float*)(ws + 73728);           // 32 KB
  double* partials = (double*)(ws + 106496);         // 1056*4 doubles = 33792 B
  double* rowpart  = (double*)(ws + 143360);         // 4*4096 doubles = 128 KB
  u32*    histbuf  = (u32*)(ws + 274432);            // 2*512*836 u32 = 3.42 MB
  u16*    Xbf      = (u16*)(ws + (4u<<20));          // 1 MB
  size_t need = (size_t)(4u<<20) + (size_t)2*NPTS*DIM*2;   // ~5.2 MB

  if (ws_size < need) return;

  // full-matrix ranks: diag(4096 zeros) + doubled upper-tri; m_ut = 8386560
  const u32 KF1 = 4096u + 2u*4193279u;   // 8390654
  const u32 KF2 = 4096u + 2u*4193280u;   // 8390656

  convert_k<<<32,256,0,stream>>>(X, Y, Xbf, Gall);
  hist_k<<<dim3(2*NREP/2,2),256,0,stream>>>(Xbf, Gall, histbuf);   // grid (512,2)
  scan16i<<<2,256,0,stream>>>(histbuf, scal, KF1, KF2);
  rowsum_k<<<dim3(512,2),256,0,stream>>>(Xbf, Gall, scal, rowpart);
  reduce_rows<<<1,256,0,stream>>>(rowpart, rowK, rowL, sums);
  final_k<<<2*NBLK,256,0,stream>>>(Xbf, Gall, scal, rowK, rowL, sums, partials);
  finalize_k<<<1,256,0,stream>>>(partials, sums, out);
}

// Round 13
// 165.962 us; speedup vs baseline: 1.2930x; 1.2930x over previous
//
#include <hip/hip_runtime.h>

typedef unsigned int u32;
typedef unsigned short u16;
typedef __attribute__((ext_vector_type(8))) short bf16x8;   // 8 bf16 in 4 VGPRs
typedef __attribute__((ext_vector_type(4))) float f32x4;

#define NPTS 4096
#define DIM  64
#define NB   32          // 4096/128
#define TS   128
#define NBLK 528         // NB*(NB+1)/2 upper-tri blocks (final_k only)
#define WLO16 0x4140u    // window low: float bits 0x41400000 = 12.0
#define NWBIN 832        // t16 in [0x4140, 0x4480) -> D in [12, 1024)
#define RSTR 836         // replica stride in u32
#define NREP 512         // per-z histogram replicas

// Swizzled fragment-major layout (chunk = bf16x8 = 16 B):
//   chunk_index(row, f) = (row>>4)*128 + f*16 + (row&15)
// => wave load for (group g, frag f): lane(q,nl) reads g*128 + f*16 + nl  -> lane-contiguous.

// map linear upper-tri block id -> (by,bx), bx>=by  (final_k)
__device__ __forceinline__ void bmap(int b, int& by, int& bx){
  by = 0;
  while (b >= NB - by){ b -= NB - by; by++; }
  bx = by + b;
}

// fp32 -> bf16 bits, round-nearest-even
__device__ __forceinline__ u16 f2bf(float x){
  u32 u = __float_as_uint(x);
  return (u16)((u + 0x7fffu + ((u>>16)&1u)) >> 16);
}

// ---------- pre-pass: X,Y -> swizzled bf16 fragments + fp32 squared norms ----------
__global__ __launch_bounds__(256) void convert_k(const float* __restrict__ X, const float* __restrict__ Y,
                                                 u16* __restrict__ Xbf, float* __restrict__ Gall){
  int t = blockIdx.x*256 + threadIdx.x;     // 8192 threads, one row each
  int z = t >> 12, row = t & 4095;
  const float* src = (z ? Y : X) + (size_t)row*DIM;
  // chunk units (16 B = 8 bf16)
  u16* base = Xbf + ((size_t)z*32768 + (size_t)(row>>4)*128 + (row&15))*8;
  float g = 0.f;
#pragma unroll
  for (int f=0; f<8; f++){
    float4 f0 = *(const float4*)(src + f*8);
    float4 f1 = *(const float4*)(src + f*8 + 4);
    g = fmaf(f0.x,f0.x,g); g = fmaf(f0.y,f0.y,g); g = fmaf(f0.z,f0.z,g); g = fmaf(f0.w,f0.w,g);
    g = fmaf(f1.x,f1.x,g); g = fmaf(f1.y,f1.y,g); g = fmaf(f1.z,f1.z,g); g = fmaf(f1.w,f1.w,g);
    ushort4 h0, h1;
    h0.x=f2bf(f0.x); h0.y=f2bf(f0.y); h0.z=f2bf(f0.z); h0.w=f2bf(f0.w);
    h1.x=f2bf(f1.x); h1.y=f2bf(f1.y); h1.z=f2bf(f1.z); h1.w=f2bf(f1.w);
    u16* dst = base + (size_t)f*16*8;
    *(ushort4*)dst = h0;
    *(ushort4*)(dst+4) = h1;
  }
  Gall[t] = g;
}

// ---------- pass 1: full-matrix panel histogram (coalesced swizzled loads, no global atomics) ----------
__global__ __launch_bounds__(256,2) void hist_k(const u16* __restrict__ Xbf, const float* __restrict__ Gall,
                                                u32* __restrict__ histbuf){
  __shared__ u32 lh[RSTR];
  int z = blockIdx.y, tid = threadIdx.x;
  int pb = blockIdx.x;              // 0..511
  int pa = pb >> 1, ch = pb & 1;
  int w=tid>>6, lane=tid&63, q=lane>>4, nl=lane&15;
  for (int t=tid;t<RSTR;t+=256) lh[t]=0;
  __syncthreads();
  const bf16x8* Xb = (const bf16x8*)Xbf + (size_t)z*32768;
  const float* Gz = Gall + z*NPTS;
  bf16x8 af0 = Xb[pa*128 + q*16 + nl];
  bf16x8 af1 = Xb[pa*128 + (4+q)*16 + nl];
  float ga = Gz[pa*16 + nl];
  float gAm[4];
#pragma unroll
  for (int r=0;r<4;r++) gAm[r] = __shfl(ga, q*4+r, 64);
  for (int it=0; it<4; ++it){
    int jg0 = ch*128 + (it*4 + w)*8;           // 16-row group index of j0
    f32x4 acc[8];
#pragma unroll
    for (int b=0;b<8;b++) acc[b] = (f32x4)0.0f;
#pragma unroll
    for (int tb=0;tb<8;tb++){
      int jg = jg0 + tb;
      acc[tb] = __builtin_amdgcn_mfma_f32_16x16x32_bf16(af0, Xb[jg*128 + q*16 + nl],     acc[tb], 0,0,0);
      acc[tb] = __builtin_amdgcn_mfma_f32_16x16x32_bf16(af1, Xb[jg*128 + (4+q)*16 + nl], acc[tb], 0,0,0);
    }
#pragma unroll
    for (int tb=0;tb<8;tb++){
      int j = (jg0 + tb)*16 + nl;
      float gb = Gz[j];
#pragma unroll
      for (int r=0;r<4;r++){
        int i = pa*16 + q*4 + r;
        float d = (gAm[r] + gb) - 2.0f*acc[tb][r];
        if (i==j) d = 0.f;                       // diag -> bin 0 (below window)
        u32 t16 = __float_as_uint(d) >> 16;
        u32 bin = (t16 < WLO16) ? 0u
                : (t16 >= WLO16+NWBIN) ? (u32)(NWBIN+1)
                : (t16 - WLO16 + 1u);
        atomicAdd(&lh[bin], 1u);
      }
    }
  }
  __syncthreads();
  u32* dst = histbuf + ((size_t)z*NREP + pb)*RSTR;
  for (int t=tid;t<RSTR;t+=256) dst[t] = lh[t];
}

// ---------- reduce 512 replicas -> histsum[2][836] (bin-per-thread, coalesced) ----------
__global__ __launch_bounds__(256) void reduce_hist(const u32* __restrict__ histbuf,
                                                   u32* __restrict__ histsum){
  int t = blockIdx.x*256 + threadIdx.x;
  if (t >= 2*RSTR) return;
  int z = t / RSTR, bin = t - z*RSTR;
  const u32* base = histbuf + (size_t)z*NREP*RSTR + bin;
  u32 s = 0;
  for (int rep=0; rep<NREP; rep++) s += base[(size_t)rep*RSTR];
  histsum[t] = s;
}

// ---------- parallel select + interpolate from reduced hist ----------
// full-matrix ranks: kf = 4096 (diag zeros) + 2*k_uppertri
__global__ __launch_bounds__(256) void scan16i(const u32* __restrict__ histsum,
                                               float* __restrict__ scal,
                                               u32 kf1, u32 kf2){
  int z = blockIdx.x;
  int tid = threadIdx.x;
  __shared__ u32 wsum[4];
  __shared__ double svals[2];
  u32 c4[4] = {0,0,0,0};
  if (tid < 209){
    const u32* base = histsum + (size_t)z*RSTR + 4*tid;
    int lim = RSTR - 4*tid;
    c4[0] = base[0];
    if (lim>1) c4[1] = base[1];
    if (lim>2) c4[2] = base[2];
    if (lim>3) c4[3] = base[3];
  }
  u32 s = c4[0]+c4[1]+c4[2]+c4[3];
  int lane = tid & 63, wv = tid >> 6;
  u32 pre = s;
#pragma unroll
  for (int off=1; off<64; off<<=1){
    u32 t2 = __shfl_up(pre, off, 64);
    if (lane >= off) pre += t2;
  }
  if (lane==63) wsum[wv] = pre;
  __syncthreads();
  u32 base2 = 0;
  for (int k=0;k<wv;k++) base2 += wsum[k];
  u32 incl = base2 + pre, excl = incl - s;
  u32 ks[2] = {kf1,kf2};
#pragma unroll
  for (int w2=0; w2<2; w2++){
    if (ks[w2] >= excl && ks[w2] < incl){
      u32 acc = excl;
#pragma unroll
      for (int j=0;j<4;j++){
        if (ks[w2] < acc + c4[j]){
          int b = tid*4 + j;
          double lo, hi;
          if (b==0){ lo=12.0; hi=12.0; }
          else if (b>=NWBIN+1){ lo=1024.0; hi=1024.0; }
          else {
            u32 t16 = WLO16 + (u32)b - 1u;
            lo = (double)__uint_as_float(t16<<16);
            hi = (double)__uint_as_float((t16+1u)<<16);
          }
          double frac = ((double)(ks[w2]-acc) + 0.5)/(double)c4[j];
          svals[w2] = lo + (hi-lo)*frac;
          break;
        }
        acc += c4[j];
      }
    }
  }
  __syncthreads();
  if (tid==0){
    float med = (float)(0.5*(svals[0]+svals[1]));
    float wd = sqrtf(0.5f*med);
    scal[z] = 2.0f*wd*wd;
  }
}

// ---------- pass 2: full-matrix panel row sums, plain stores ----------
__global__ __launch_bounds__(256,2) void rowsum_k(const u16* __restrict__ Xbf, const float* __restrict__ Gall,
                                                  const float* __restrict__ scal,
                                                  double* __restrict__ rowpart){   // [z*2+ch][4096]
  int z = blockIdx.y, tid = threadIdx.x;
  int pb = blockIdx.x;
  int pa = pb >> 1, ch = pb & 1;
  int w=tid>>6, lane=tid&63, q=lane>>4, nl=lane&15;
  const bf16x8* Xb = (const bf16x8*)Xbf + (size_t)z*32768;
  const float* Gz = Gall + z*NPTS;
  float negi = -1.0f/scal[z];
  bf16x8 af0 = Xb[pa*128 + q*16 + nl];
  bf16x8 af1 = Xb[pa*128 + (4+q)*16 + nl];
  float ga = Gz[pa*16 + nl];
  float gAm[4];
#pragma unroll
  for (int r=0;r<4;r++) gAm[r] = __shfl(ga, q*4+r, 64);
  double rs[4] = {0,0,0,0};
  for (int it=0; it<4; ++it){
    int jg0 = ch*128 + (it*4 + w)*8;
    f32x4 acc[8];
#pragma unroll
    for (int b=0;b<8;b++) acc[b] = (f32x4)0.0f;
#pragma unroll
    for (int tb=0;tb<8;tb++){
      int jg = jg0 + tb;
      acc[tb] = __builtin_amdgcn_mfma_f32_16x16x32_bf16(af0, Xb[jg*128 + q*16 + nl],     acc[tb], 0,0,0);
      acc[tb] = __builtin_amdgcn_mfma_f32_16x16x32_bf16(af1, Xb[jg*128 + (4+q)*16 + nl], acc[tb], 0,0,0);
    }
#pragma unroll
    for (int tb=0;tb<8;tb++){
      int j = (jg0 + tb)*16 + nl;
      float gb = Gz[j];
#pragma unroll
      for (int r=0;r<4;r++){
        int i = pa*16 + q*4 + r;
        float d = (gAm[r] + gb) - 2.0f*acc[tb][r];
        if (i==j) d = 0.f;                       // exact K_ii = 1
        rs[r] += (double)expf(d*negi);
      }
    }
  }
#pragma unroll
  for (int r=0;r<4;r++){
    double v2 = rs[r];
    v2 += __shfl_xor(v2,1,64); v2 += __shfl_xor(v2,2,64);
    v2 += __shfl_xor(v2,4,64); v2 += __shfl_xor(v2,8,64);
    rs[r] = v2;
  }
  __shared__ double rsum[4][16];
  if (nl==0){
#pragma unroll
    for (int r=0;r<4;r++) rsum[w][q*4+r] = rs[r];
  }
  __syncthreads();
  if (tid < 16){
    double s = rsum[0][tid]+rsum[1][tid]+rsum[2][tid]+rsum[3][tid];
    rowpart[(size_t)(z*2+ch)*NPTS + pa*16 + tid] = s;
  }
}

// ---------- combine halves -> rowK/rowL + totals ----------
__global__ __launch_bounds__(256) void reduce_rows(const double* __restrict__ rowpart,
                                                   double* __restrict__ rowK, double* __restrict__ rowL,
                                                   double* __restrict__ sums){
  __shared__ double sd[256];
  int t=threadIdx.x;
  double s0=0, s1=0;
  for (int i=t;i<NPTS;i+=256){
    double a = rowpart[i] + rowpart[NPTS+i];
    double b = rowpart[2*NPTS+i] + rowpart[3*NPTS+i];
    rowK[i]=a; rowL[i]=b;
    s0+=a; s1+=b;
  }
  sd[t]=s0; __syncthreads();
  for(int off=128;off>0;off>>=1){ if(t<off) sd[t]+=sd[t+off]; __syncthreads(); }
  if(t==0) sums[0]=sd[0];
  __syncthreads();
  sd[t]=s1; __syncthreads();
  for(int off=128;off>0;off>>=1){ if(t<off) sd[t]+=sd[t+off]; __syncthreads(); }
  if(t==0) sums[1]=sd[0];
}

// ---------- pass 3: centered products (half-tile blocks, swizzled loads) ----------
__global__ __launch_bounds__(256,2) void final_k(const u16* __restrict__ Xbf, const float* __restrict__ Gall,
                                                 const float* __restrict__ scal,
                                                 const double* __restrict__ rowK,
                                                 const double* __restrict__ rowL,
                                                 const double* __restrict__ sums,
                                                 double* __restrict__ partials){
  int tid = threadIdx.x;
  int b = blockIdx.x >> 1, half = blockIdx.x & 1;
  int by,bx; bmap(b,by,bx);
  bool isdiag = (by==bx);
  int w=tid>>6, lane=tid&63, q=lane>>4, nl=lane&15;
  const bf16x8* Xb = (const bf16x8*)Xbf;
  const bf16x8* Yb = Xb + 32768;
  const float* Gx = Gall;
  const float* Gy = Gall + NPTS;
  const double inv_n = 1.0/(double)NPTS;
  double tmK = sums[0]*(inv_n*inv_n), tmL = sums[1]*(inv_n*inv_n);
  float negx = -1.0f/scal[0], negy = -1.0f/scal[1];
  double wgt = isdiag ? 1.0 : 2.0;
  double S1=0, S2=0, trV=0;
  int rt = half*4 + w;
  int ag = by*8 + rt;                       // A 16-row group index
  bf16x8 axf0 = Xb[ag*128 + q*16 + nl];
  bf16x8 axf1 = Xb[ag*128 + (4+q)*16 + nl];
  bf16x8 ayf0 = Yb[ag*128 + q*16 + nl];
  bf16x8 ayf1 = Yb[ag*128 + (4+q)*16 + nl];
  int rowA = ag*16 + nl;
  float gaX = Gx[rowA], gaY = Gy[rowA];
  float gXm[4], gYm[4];
#pragma unroll
  for (int r=0;r<4;r++){ gXm[r] = __shfl(gaX, q*4+r, 64); gYm[r] = __shfl(gaY, q*4+r, 64); }
  double rmKi[4], rmLi[4];
#pragma unroll
  for (int r=0;r<4;r++){
    int i = ag*16 + q*4 + r;
    rmKi[r] = rowK[i]*inv_n; rmLi[r] = rowL[i]*inv_n;
  }
#pragma unroll
  for (int tb=0;tb<8;tb++){
    int jg = bx*8 + tb;
    f32x4 accX = (f32x4)0.0f, accY = (f32x4)0.0f;
    accX = __builtin_amdgcn_mfma_f32_16x16x32_bf16(axf0, Xb[jg*128 + q*16 + nl],     accX, 0,0,0);
    accX = __builtin_amdgcn_mfma_f32_16x16x32_bf16(axf1, Xb[jg*128 + (4+q)*16 + nl], accX, 0,0,0);
    accY = __builtin_amdgcn_mfma_f32_16x16x32_bf16(ayf0, Yb[jg*128 + q*16 + nl],     accY, 0,0,0);
    accY = __builtin_amdgcn_mfma_f32_16x16x32_bf16(ayf1, Yb[jg*128 + (4+q)*16 + nl], accY, 0,0,0);
    int j = jg*16 + nl;
    float gbX = Gx[j], gbY = Gy[j];
    double cmK = rowK[j]*inv_n - tmK;
    double cmL = rowL[j]*inv_n - tmL;
#pragma unroll
    for (int r=0;r<4;r++){
      int i = ag*16 + q*4 + r;
      float dx = (gXm[r] + gbX) - 2.0f*accX[r];
      float dy = (gYm[r] + gbY) - 2.0f*accY[r];
      bool dg = isdiag && i==j;
      if (dg){ dx = 0.f; dy = 0.f; }
      float kx = expf(dx*negx);
      float lv = expf(dy*negy);
      double kc = ((double)kx - rmKi[r]) - cmK;
      double lc = ((double)lv - rmLi[r]) - cmL;
      double prod = kc*lc;
      S1 += wgt*prod;
      double vv = (prod*prod)*(1.0/36.0);
      S2 += wgt*vv;
      if (dg) trV += vv;
    }
  }
  __shared__ double red[4][3];
  double vals[3]={S1,S2,trV};
  int wv = tid >> 6;
#pragma unroll
  for (int v=0;v<3;v++){
    double x = vals[v];
#pragma unroll
    for (int s2=1;s2<64;s2<<=1) x += __shfl_xor(x, s2, 64);
    if (lane==0) red[wv][v]=x;
  }
  __syncthreads();
  if (tid < 3)
    partials[(size_t)blockIdx.x*4 + tid] = red[0][tid]+red[1][tid]+red[2][tid]+red[3][tid];
}

// ---------- wave-parallel regularized lower incomplete gamma P(a,x) ----------
__device__ double gammainc_wave(double a, double x, double lga, int lane){
  double C = 1.0/a;
  double psum = 0.0;
  for (int b=0;b<8192;b++){
    double k = (double)(b*64 + lane + 1);
    double rr = x/(a+k);
    double pp = rr;
#pragma unroll
    for (int s=1;s<64;s<<=1){
      double t = __shfl_up(pp, s, 64);
      if (lane >= s) pp *= t;
    }
    double c = C*pp;
    psum += c;
    double clast = __shfl(c, 63, 64);
    double rlast = __shfl(rr, 63, 64);
    C = clast;
    if (rlast < 1.0 && clast*rlast/(1.0-rlast) < 1e-17) break;
  }
#pragma unroll
  for (int s=1;s<64;s<<=1) psum += __shfl_xor(psum, s, 64);
  double total = 1.0/a + psum;
  return exp(-x + a*log(x) - lga) * total;
}

// ---------- reduce partials + Newton ----------
__global__ __launch_bounds__(256) void finalize_k(const double* __restrict__ partials,
                                                  const double* __restrict__ sums,
                                                  float* __restrict__ out)
{
  __shared__ double red[3][4];
  __shared__ double tot[4];
  int tid = threadIdx.x;
  double v0=0,v1=0,v2=0;
  for (int i=tid; i<2*NBLK; i+=256){
    const double* p = partials + (size_t)i*4;
    v0+=p[0]; v1+=p[1]; v2+=p[2];
  }
  double vals[3]={v0,v1,v2};
  int lane = tid & 63, wv = tid >> 6;
#pragma unroll
  for (int v=0;v<3;v++){
    double x = vals[v];
#pragma unroll
    for (int s2=1;s2<64;s2<<=1) x += __shfl_xor(x, s2, 64);
    if (lane==0) red[v][wv]=x;
  }
  __syncthreads();
  if (tid==0){
#pragma unroll
    for (int v=0;v<3;v++) tot[v] = red[v][0]+red[v][1]+red[v][2]+red[v][3];
  }
  __syncthreads();
  if (tid >= 64) return;

  const double n = (double)NPTS;
  double totK=sums[0], totL=sums[1];
  double S1=tot[0], S2=tot[1], trV=tot[2];
  double testStat = S1/n;
  double varHSIC = (S2 - trV)/n/(n-1.0);
  varHSIC = varHSIC*72.0*(n-4.0)*(n-5.0)/n/(n-1.0)/(n-2.0)/(n-3.0);
  double muX = (totK-n)/n/(n-1.0);   // trace(K) = n exactly (diag forced to 1)
  double muY = (totL-n)/n/(n-1.0);
  double mHSIC = (1.0 + muX*muY - muX - muY)/n;
  double al = mHSIC*mHSIC/varHSIC;
  double bet = varHSIC*n/mHSIC;
  double p = (double)((float)(1.0-0.8));
  double lga = lgamma(al);
  double lo = 0.0, hi = al + 10.0*sqrt(al) + 100.0;
  const double zp = -0.8416212335729142957;  // Phi^-1(0.2)
  double t = 1.0 - 1.0/(9.0*al) + zp/(3.0*sqrt(al));
  double x = al*t*t*t;
  if (!(x > 0.0) || !(x < hi)) x = 0.5*hi;
  for (int it=0; it<2; ++it){
    double P = gammainc_wave(al, x, lga, lane);
    double diff = P - p;
    if (diff < 0.0) lo = x; else hi = x;
    if (fabs(diff) < 1e-12) break;
    double pdf = exp(-x + (al-1.0)*log(x) - lga);
    double nx = x - diff/pdf;
    if (!(nx > lo) || !(nx < hi)) nx = 0.5*(lo+hi);
    x = nx;
  }
  if (lane==0){
    out[0]=(float)testStat;
    out[1]=(float)(bet*x);
  }
}

// ---------- host ----------
extern "C" void kernel_launch(void* const* d_in, const int* in_sizes, int n_in,
                              void* d_out, int out_size, void* d_ws, size_t ws_size,
                              hipStream_t stream) {
  const float* X = (const float*)d_in[0];
  const float* Y = (const float*)d_in[1];
  float* out = (float*)d_out;
  char* ws = (char*)d_ws;

  double* sums     = (double*)ws;                    // 2 doubles @0
  float*  scal     = (float*)(ws + 128);             // 2 floats
  u32*    histsum  = (u32*)(ws + 256);               // 2*836 u32 = 6688 B
  double* rowK     = (double*)(ws + 8192);           // 32 KB
  double* rowL     = (double*)(ws + 40960);          // 32 KB
  float*  Gall     = (float*)(ws + 73728);           // 32 KB
  double* partials = (double*)(ws + 106496);         // 1056*4 doubles = 33792 B
  double* rowpart  = (double*)(ws + 143360);         // 4*4096 doubles = 128 KB
  u32*    histbuf  = (u32*)(ws + 274432);            // 2*512*836 u32 = 3.42 MB
  u16*    Xbf      = (u16*)(ws + (4u<<20));          // 1 MB (swizzled fragment-major)
  size_t need = (size_t)(4u<<20) + (size_t)2*NPTS*DIM*2;   // ~5.2 MB

  if (ws_size < need) return;

  // full-matrix ranks: diag(4096 zeros) + doubled upper-tri; m_ut = 8386560
  const u32 KF1 = 4096u + 2u*4193279u;   // 8390654
  const u32 KF2 = 4096u + 2u*4193280u;   // 8390656

  convert_k<<<32,256,0,stream>>>(X, Y, Xbf, Gall);
  hist_k<<<dim3(NREP,2),256,0,stream>>>(Xbf, Gall, histbuf);
  reduce_hist<<<(2*RSTR+255)/256,256,0,stream>>>(histbuf, histsum);
  scan16i<<<2,256,0,stream>>>(histsum, scal, KF1, KF2);
  rowsum_k<<<dim3(NREP,2),256,0,stream>>>(Xbf, Gall, scal, rowpart);
  reduce_rows<<<1,256,0,stream>>>(rowpart, rowK, rowL, sums);
  final_k<<<2*NBLK,256,0,stream>>>(Xbf, Gall, scal, rowK, rowL, sums, partials);
  finalize_k<<<1,256,0,stream>>>(partials, sums, out);
}